// Round 8
// baseline (221.442 us; speedup 1.0000x reference)
//
#include <hip/hip_runtime.h>

typedef unsigned short u16;
typedef unsigned int u32;

typedef __bf16 bf16x8 __attribute__((ext_vector_type(8)));
typedef float f32x4 __attribute__((ext_vector_type(4)));

union V16 { uint4 u; bf16x8 v; u16 s[8]; __bf16 h[8]; };
union F4  { float4 v; float f[4]; };

__device__ __forceinline__ float bf2f(u16 a) {
  union { u32 u; float f; } c; c.u = ((u32)a) << 16; return c.f;
}

#define Z_OFF   131072
#define ZM_OFF  147456
#define ZLV_OFF 163840

// ws layout in uint4 units (decoder-only now):
// b-frag elem j of lane: B[k=s*32+(lane>>4)*8+j][n=t*16+(lane&15)]
#define B1_OFF 0        // gen1_w frags: t<20, s<2    (2560)
#define B2_OFF 2560     // gen2_w frags: t<20, s<10   (12800)
#define WB4    15360    // W bf16 [512][64] row-major (4096)
#define PACK_ITEMS 19456
#define ENC_WGS 16
#define PREP_WGS (ENC_WGS + PACK_ITEMS / 256)   // 92

__device__ __forceinline__ void pack_one(const float* __restrict__ src,
                                         int t, int s, int lane,
                                         int Nsrc, int Ksrc, int rowlen,
                                         uint4* __restrict__ dst) {
  const int n = t * 16 + (lane & 15);
  const int k0 = s * 32 + ((lane >> 4) << 3);
  V16 v;
#pragma unroll
  for (int j = 0; j < 8; ++j) {
    const int k = k0 + j;
    v.h[j] = (n < Nsrc && k < Ksrc) ? (__bf16)src[n * rowlen + k] : (__bf16)0.f;
  }
  *dst = v.u;
}

__device__ __forceinline__ void cvt8(const float* __restrict__ src, uint4* __restrict__ dst) {
  F4 a, b; a.v = *(const float4*)src; b.v = *(const float4*)(src + 4);
  V16 v;
#pragma unroll
  for (int j = 0; j < 4; ++j) { v.h[j] = (__bf16)a.f[j]; v.h[4 + j] = (__bf16)b.f[j]; }
  *dst = v.u;
}

// Build a B-fragment on the fly from fp32 row-major [Nsrc][rowlen].
// n = tile*16 + c (lane col), k0 = s*32 + q*8. Vector path when the 8-wide
// k-window is fully in-bounds; masked scalar path on the K tail.
__device__ __forceinline__ bf16x8 bfrag(const float* __restrict__ src,
                                        int n, int k0, int Nsrc, int Ksrc,
                                        int rowlen) {
  V16 m;
  if (n < Nsrc && k0 + 8 <= Ksrc) {
    F4 a, b;
    a.v = *(const float4*)(src + n * rowlen + k0);
    b.v = *(const float4*)(src + n * rowlen + k0 + 4);
#pragma unroll
    for (int j = 0; j < 4; ++j) { m.h[j] = (__bf16)a.f[j]; m.h[4 + j] = (__bf16)b.f[j]; }
  } else if (n < Nsrc) {
#pragma unroll
    for (int j = 0; j < 8; ++j) {
      const int k = k0 + j;
      m.h[j] = (k < Ksrc) ? (__bf16)src[n * rowlen + k] : (__bf16)0.f;
    }
  } else {
#pragma unroll
    for (int j = 0; j < 8; ++j) m.h[j] = (__bf16)0.f;
  }
  return m.v;
}

// ---------------------------------------------------------------------------
// prep: WGs 0..15 = full encoder (16 batch rows each, weights read direct from
// global, frags built on the fly); WGs 16..91 = pack b1p/b2p/Wb for decoder.
// ---------------------------------------------------------------------------
__global__ __launch_bounds__(256, 2) void prep_kernel(
    const float* __restrict__ x, const float* __restrict__ eps,
    const float* __restrict__ e1w, const float* __restrict__ e1b,
    const float* __restrict__ e2w, const float* __restrict__ e2b,
    const float* __restrict__ zmw, const float* __restrict__ zmb,
    const float* __restrict__ zvw, const float* __restrict__ zvb,
    const float* __restrict__ g1w, const float* __restrict__ g2w,
    const float* __restrict__ W,
    uint4* __restrict__ ws4, float* __restrict__ out) {
  if (blockIdx.x >= ENC_WGS) {
    const int idx = (blockIdx.x - ENC_WGS) * 256 + threadIdx.x;
    const int lane = idx & 63;
    if (idx < B2_OFF) {
      const int f = idx >> 6;
      pack_one(g1w, f >> 1, f & 1, lane, 300, 64, 64, ws4 + idx);
    } else if (idx < WB4) {
      const int f = (idx - B2_OFF) >> 6;
      pack_one(g2w, f / 10, f % 10, lane, 300, 300, 300, ws4 + idx);
    } else {
      const int i = idx - WB4;
      cvt8(W + i * 8, ws4 + WB4 + i);
    }
    return;
  }

  // ---- encoder: rows bi0..bi0+15; 4 waves, wave w owns n-tiles 5w..5w+4 ----
  __shared__ u16 h1s[16 * 328];
  __shared__ u16 h2s[16 * 328];
  const int bi0 = blockIdx.x * 16;
  const int tid = threadIdx.x;
  const int w = tid >> 6, lane = tid & 63, q = lane >> 4, c = lane & 15;

  bf16x8 af[16];
#pragma unroll
  for (int s = 0; s < 16; ++s) {
    const float* px = x + (bi0 + c) * 512 + s * 32 + q * 8;
    F4 a, b; a.v = *(const float4*)px; b.v = *(const float4*)(px + 4);
    V16 m;
#pragma unroll
    for (int j = 0; j < 4; ++j) { m.h[j] = (__bf16)a.f[j]; m.h[4 + j] = (__bf16)b.f[j]; }
    af[s] = m.v;
  }
  // layer 1 (K=512, no k-mask)
  f32x4 acc[5];
#pragma unroll
  for (int tt = 0; tt < 5; ++tt) acc[tt] = {0.f, 0.f, 0.f, 0.f};
#pragma unroll
  for (int s = 0; s < 16; ++s) {
    const int k0 = s * 32 + q * 8;
#pragma unroll
    for (int tt = 0; tt < 5; ++tt) {
      const int n = (w * 5 + tt) * 16 + c;
      bf16x8 b = bfrag(e1w, n, k0, 300, 512, 512);
      acc[tt] = __builtin_amdgcn_mfma_f32_16x16x32_bf16(af[s], b, acc[tt], 0, 0, 0);
    }
  }
#pragma unroll
  for (int tt = 0; tt < 5; ++tt) {
    const int col = (w * 5 + tt) * 16 + c;
    const float bias = (col < 300) ? e1b[col] : 0.f;
#pragma unroll
    for (int i = 0; i < 4; ++i) {
      V16 t; t.h[0] = (col < 300) ? (__bf16)fmaxf(acc[tt][i] + bias, 0.f) : (__bf16)0.f;
      h1s[(4 * q + i) * 328 + col] = t.s[0];
    }
  }
  __syncthreads();
  // layer 2 (K=300 -> masked tail at s=9)
#pragma unroll
  for (int tt = 0; tt < 5; ++tt) acc[tt] = {0.f, 0.f, 0.f, 0.f};
#pragma unroll
  for (int s = 0; s < 10; ++s) {
    V16 a; a.u = *(const uint4*)&h1s[c * 328 + s * 32 + q * 8];
    const int k0 = s * 32 + q * 8;
#pragma unroll
    for (int tt = 0; tt < 5; ++tt) {
      const int n = (w * 5 + tt) * 16 + c;
      bf16x8 b = bfrag(e2w, n, k0, 300, 300, 300);
      acc[tt] = __builtin_amdgcn_mfma_f32_16x16x32_bf16(a.v, b, acc[tt], 0, 0, 0);
    }
  }
#pragma unroll
  for (int tt = 0; tt < 5; ++tt) {
    const int col = (w * 5 + tt) * 16 + c;
    const float bias = (col < 300) ? e2b[col] : 0.f;
#pragma unroll
    for (int i = 0; i < 4; ++i) {
      V16 t; t.h[0] = (col < 300) ? (__bf16)fmaxf(acc[tt][i] + bias, 0.f) : (__bf16)0.f;
      h2s[(4 * q + i) * 328 + col] = t.s[0];
    }
  }
  __syncthreads();
  // heads: wave w does zm tile w and zv tile w (L=64 -> 4 tiles)
  f32x4 am = {0.f, 0.f, 0.f, 0.f}, av = {0.f, 0.f, 0.f, 0.f};
#pragma unroll
  for (int s = 0; s < 10; ++s) {
    V16 a; a.u = *(const uint4*)&h2s[c * 328 + s * 32 + q * 8];
    const int k0 = s * 32 + q * 8;
    const int n = w * 16 + c;   // < 64 always
    bf16x8 bm = bfrag(zmw, n, k0, 64, 300, 300);
    bf16x8 bv = bfrag(zvw, n, k0, 64, 300, 300);
    am = __builtin_amdgcn_mfma_f32_16x16x32_bf16(a.v, bm, am, 0, 0, 0);
    av = __builtin_amdgcn_mfma_f32_16x16x32_bf16(a.v, bv, av, 0, 0, 0);
  }
  const int col = w * 16 + c;
  const float bm = zmb[col], bv = zvb[col];
#pragma unroll
  for (int i = 0; i < 4; ++i) {
    const int gi = (bi0 + 4 * q + i) * 64 + col;
    const float zm = am[i] + bm;
    const float zlv = av[i] + bv;
    out[ZM_OFF + gi] = zm;
    out[ZLV_OFF + gi] = zlv;
    out[Z_OFF + gi] = zm + eps[gi] * expf(0.5f * zlv);
  }
}

// ---------------------------------------------------------------------------
// Fused decoder. 4096 WGs x 320 thr (5 waves). 32 rows/WG (one b).
// LDS 20,992 B (xred aliases g1s after barrier). Wave u owns n-tiles 4u..4u+3.
// Stage 3: 2-deep b2p software pipeline; hw/g2b hoisted into registers before
// the K-loop so their latency hides under the 80 MFMAs.
// ---------------------------------------------------------------------------
__global__ __launch_bounds__(320, 3) void dec_kernel(
    const float* __restrict__ z,     // [256][64] (fp32, in d_out)
    const uint4* __restrict__ Wb,    // bf16 [512][64]
    const uint4* __restrict__ b1p,
    const uint4* __restrict__ b2p,
    const float* __restrict__ g2b,
    const float* __restrict__ hw,    // [512][300] fp32
    const float* __restrict__ hb,
    float* __restrict__ xout) {
  __shared__ u16 g1s[32 * 328];     // 20,992 B (reused as xred after barrier)
  float* xredf = (float*)g1s;

  const int wg = blockIdx.x;
  const int r0 = wg << 5;
  const int bi = wg >> 4;
  const int d0 = r0 & 511;
  const int tid = threadIdx.x;
  const int u = tid >> 6;
  const int lane = tid & 63;
  const int q = lane >> 4;
  const int c = lane & 15;

  const float* zrow = z + bi * 64;

  // ---- stage 2 ----
  bf16x8 bz[4][2];
#pragma unroll
  for (int kf = 0; kf < 2; ++kf) {
    F4 z0, z1;
    z0.v = *(const float4*)(zrow + kf * 32 + q * 8);
    z1.v = *(const float4*)(zrow + kf * 32 + q * 8 + 4);
#pragma unroll
    for (int tt = 0; tt < 4; ++tt) {
      V16 r; r.u = b1p[((4 * u + tt) * 2 + kf) * 64 + lane];
      V16 m;
#pragma unroll
      for (int j = 0; j < 4; ++j) {
        m.h[j]     = (__bf16)(bf2f(r.s[j])     * z0.f[j]);
        m.h[4 + j] = (__bf16)(bf2f(r.s[4 + j]) * z1.f[j]);
      }
      bz[tt][kf] = m.v;
    }
  }
#pragma unroll
  for (int rt = 0; rt < 2; ++rt) {
    const int rowA = rt * 16 + c;
    V16 af0, af1;
    af0.u = Wb[(d0 + rowA) * 8 + q];
    af1.u = Wb[(d0 + rowA) * 8 + 4 + q];
    f32x4 acc[4];
#pragma unroll
    for (int tt = 0; tt < 4; ++tt) acc[tt] = {0.f, 0.f, 0.f, 0.f};
#pragma unroll
    for (int tt = 0; tt < 4; ++tt) {
      acc[tt] = __builtin_amdgcn_mfma_f32_16x16x32_bf16(af0.v, bz[tt][0], acc[tt], 0, 0, 0);
      acc[tt] = __builtin_amdgcn_mfma_f32_16x16x32_bf16(af1.v, bz[tt][1], acc[tt], 0, 0, 0);
    }
    const int rwb = rt * 16 + 4 * q;
#pragma unroll
    for (int tt = 0; tt < 4; ++tt) {
      const int colb = (4 * u + tt) * 16 + c;
#pragma unroll
      for (int i = 0; i < 4; ++i) {
        V16 t; t.h[0] = (__bf16)fmaxf(acc[tt][i], 0.f);
        g1s[(rwb + i) * 328 + colb] = t.s[0];
      }
    }
  }
  __syncthreads();

  // ---- hoist epilogue operands (latency hides under the MFMA loop) ----
  float hwv[4][2][4];
  float bias[4];
#pragma unroll
  for (int tt = 0; tt < 4; ++tt) {
    const int col = (4 * u + tt) * 16 + c;
    const bool inb = (col < 300);
    bias[tt] = inb ? g2b[col] : 0.f;
#pragma unroll
    for (int rt = 0; rt < 2; ++rt)
#pragma unroll
      for (int i = 0; i < 4; ++i)
        hwv[tt][rt][i] = inb ? hw[(d0 + rt * 16 + 4 * q + i) * 300 + col] : 0.f;
  }

  // ---- stage 3: 2-deep b2p pipeline ----
  f32x4 a3[4][2];
#pragma unroll
  for (int tt = 0; tt < 4; ++tt)
#pragma unroll
    for (int rt = 0; rt < 2; ++rt) a3[tt][rt] = {0.f, 0.f, 0.f, 0.f};
  V16 bp[2][4];
#pragma unroll
  for (int tt = 0; tt < 4; ++tt) bp[0][tt].u = b2p[((4 * u + tt) * 10 + 0) * 64 + lane];
  for (int s = 0; s < 10; ++s) {
    const int cur = s & 1, nxt = cur ^ 1;
    if (s < 9) {
#pragma unroll
      for (int tt = 0; tt < 4; ++tt)
        bp[nxt][tt].u = b2p[((4 * u + tt) * 10 + s + 1) * 64 + lane];
    }
#pragma unroll
    for (int rt = 0; rt < 2; ++rt) {
      V16 a; a.u = *(const uint4*)&g1s[(rt * 16 + c) * 328 + s * 32 + q * 8];
#pragma unroll
      for (int tt = 0; tt < 4; ++tt)
        a3[tt][rt] = __builtin_amdgcn_mfma_f32_16x16x32_bf16(a.v, bp[cur][tt].v, a3[tt][rt], 0, 0, 0);
    }
  }

  float xacc[2][4];
#pragma unroll
  for (int rt = 0; rt < 2; ++rt)
#pragma unroll
    for (int i = 0; i < 4; ++i) xacc[rt][i] = 0.f;
#pragma unroll
  for (int tt = 0; tt < 4; ++tt)
#pragma unroll
    for (int rt = 0; rt < 2; ++rt)
#pragma unroll
      for (int i = 0; i < 4; ++i)
        xacc[rt][i] += fmaxf(a3[tt][rt][i] + bias[tt], 0.f) * hwv[tt][rt][i];

#pragma unroll
  for (int rt = 0; rt < 2; ++rt)
#pragma unroll
    for (int i = 0; i < 4; ++i) {
      float t = xacc[rt][i];
      t += __shfl_xor(t, 1);
      t += __shfl_xor(t, 2);
      t += __shfl_xor(t, 4);
      t += __shfl_xor(t, 8);
      xacc[rt][i] = t;
    }
  __syncthreads();   // all waves done with g1s; alias as xred
  if (c < 4) {
#pragma unroll
    for (int rt = 0; rt < 2; ++rt) {
      float t = xacc[rt][0];
      t = (c == 1) ? xacc[rt][1] : t;
      t = (c == 2) ? xacc[rt][2] : t;
      t = (c == 3) ? xacc[rt][3] : t;
      xredf[u * 32 + rt * 16 + 4 * q + c] = t;
    }
  }
  __syncthreads();
  if (tid < 32) {
    float t = hb[d0 + tid];
#pragma unroll
    for (int uu = 0; uu < 5; ++uu) t += xredf[uu * 32 + tid];
    xout[r0 + tid] = t;
  }
}

extern "C" void kernel_launch(void* const* d_in, const int* in_sizes, int n_in,
                              void* d_out, int out_size, void* d_ws, size_t ws_size,
                              hipStream_t stream) {
  const float* x   = (const float*)d_in[0];
  const float* eps = (const float*)d_in[1];
  const float* W   = (const float*)d_in[2];
  const float* e1w = (const float*)d_in[3];
  const float* e1b = (const float*)d_in[4];
  const float* e2w = (const float*)d_in[5];
  const float* e2b = (const float*)d_in[6];
  const float* zmw = (const float*)d_in[7];
  const float* zmb = (const float*)d_in[8];
  const float* zvw = (const float*)d_in[9];
  const float* zvb = (const float*)d_in[10];
  const float* g1w = (const float*)d_in[11];
  const float* g2w = (const float*)d_in[12];
  const float* g2b = (const float*)d_in[13];
  const float* hw  = (const float*)d_in[14];
  const float* hb  = (const float*)d_in[15];
  float* out = (float*)d_out;
  uint4* ws4 = (uint4*)d_ws;

  prep_kernel<<<PREP_WGS, 256, 0, stream>>>(x, eps, e1w, e1b, e2w, e2b,
                                            zmw, zmb, zvw, zvb, g1w, g2w, W,
                                            ws4, out);
  dec_kernel<<<4096, 320, 0, stream>>>(out + Z_OFF, ws4 + WB4,
                                       ws4 + B1_OFF, ws4 + B2_OFF,
                                       g2b, hw, hb, out);
}